// Round 5
// baseline (2405.696 us; speedup 1.0000x reference)
//
#include <hip/hip_runtime.h>
#include <hip/hip_bf16.h>
#include <math.h>

// ---- problem constants (B=32, H=W=56, C=384, WS=7, SHIFT=3) ----
#define TOKENS   100352      // 32 * 56 * 56
#define CDIM     384
#define SEQ      49
#define NHEADS   12
#define HDIM     32
#define QKVD     1152
#define HIDD     1536
#define IMG      56

typedef __attribute__((ext_vector_type(8))) short  short8;   // 8 bf16 (4 VGPRs)
typedef __attribute__((ext_vector_type(4))) float  f32x4;    // MFMA C/D

// window-token index -> pixel-row index (same (+3 mod 56) bijection fwd & inv)
__device__ __forceinline__ int token_to_pixel(int m) {
    int w  = m / SEQ, s = m % SEQ;
    int b  = w >> 6, wr = w & 63;
    int wy = wr >> 3, wx = wr & 7;
    int sy = s / 7,  sx = s % 7;
    int y = wy * 7 + sy + 3; if (y >= IMG) y -= IMG;
    int x = wx * 7 + sx + 3; if (x >= IMG) x -= IMG;
    return b * (IMG * IMG) + y * IMG + x;
}

// fp32 -> (hi, lo) bf16 split:  v ~= hi + lo, |lo| <= 2^-9 |v|
__device__ __forceinline__ void split2(float v, __hip_bfloat16& hi, __hip_bfloat16& lo) {
    hi = __float2bfloat16(v);
    lo = __float2bfloat16(v - __bfloat162float(hi));
}

// async global->LDS, 16B per lane; LDS base must be wave-uniform
__device__ __forceinline__ void gload16(const void* g, void* l) {
    __builtin_amdgcn_global_load_lds((const __attribute__((address_space(1))) void*)g,
                                     (__attribute__((address_space(3))) void*)l, 16, 0, 0);
}

// ---------------- LayerNorm -> packed [local_m][2*384] bf16 (hi|lo) --------
// WINDOWED=1: gather x[pixel(mbase+bid)] (LN1+shift+window)
// WINDOWED=0: in is pre-offset to the chunk; reads row bid (LN2)
template<int WINDOWED>
__global__ __launch_bounds__(128)
void ln_pack_kernel(const float* __restrict__ in, const float* __restrict__ w,
                    const float* __restrict__ b, __hip_bfloat16* __restrict__ out,
                    int mbase)
{
    const int ml  = blockIdx.x;
    const int src = WINDOWED ? token_to_pixel(mbase + ml) : ml;
    const float* row = in + (size_t)src * CDIM;
    const int t = threadIdx.x;

    float v0 = row[t], v1 = row[t + 128], v2 = row[t + 256];
    float s  = v0 + v1 + v2;
    float ss = fmaf(v0, v0, fmaf(v1, v1, v2 * v2));
    #pragma unroll
    for (int off = 1; off < 64; off <<= 1) {
        s  += __shfl_xor(s,  off, 64);
        ss += __shfl_xor(ss, off, 64);
    }
    __shared__ float l1[2], l2[2];
    if ((t & 63) == 0) { l1[t >> 6] = s; l2[t >> 6] = ss; }
    __syncthreads();
    float S  = l1[0] + l1[1];
    float SS = l2[0] + l2[1];
    float mean = S * (1.0f / CDIM);
    float var  = SS * (1.0f / CDIM) - mean * mean;
    float rstd = rsqrtf(var + 1e-5f);

    __hip_bfloat16* orow = out + (size_t)ml * (2 * CDIM);
    #pragma unroll
    for (int q = 0; q < 3; ++q) {
        int c = t + q * 128;
        float v = (q == 0 ? v0 : q == 1 ? v1 : v2);
        float y = (v - mean) * rstd * w[c] + b[c];
        split2(y, orow[c], orow[CDIM + c]);
    }
}

// ---------------- weight fp32 [N][K] -> packed bf16 [N][2K] (hi|lo) --------
__global__ __launch_bounds__(256)
void pack_w_kernel(const float* __restrict__ W, __hip_bfloat16* __restrict__ Wp,
                   int N, int K)
{
    const int total = N * K;
    for (int i = blockIdx.x * 256 + threadIdx.x; i < total; i += gridDim.x * 256) {
        int n = i / K, k = i % K;
        split2(W[i], Wp[(size_t)n * 2 * K + k], Wp[(size_t)n * 2 * K + K + k]);
    }
}

// ---------------- bf16x3 split GEMM: C[M,N] = A[M,K] @ B[N,K]^T ------------
// A2 [M][2K], B2 [N][2K] packed bf16 (hi|lo). Single K-sweep; per 32-wide
// K-stage stages A-hi/A-lo/B-hi/B-lo together, 48 MFMAs per barrier pair.
// 128x128 tile, 4 waves, 4x4 16x16x32-MFMA frags per wave.
// LDS slot swizzle (both-sides): LDS[row][p] holds global slot p^((row>>1)&3).
// XCD-aware bijective block swizzle (m204): contiguous tile-chunks per XCD so
// blocks sharing an A panel share one L2.
// MODE 0: fp32 C = acc + bias                       (qkv, chunk-local C)
// MODE 1: scatter fp32 C[pix(mbase+row)] = resid+acc+b  (proj+unwindow+resid)
// MODE 2: packed bf16 C = split(gelu(acc + bias))   (fc1, chunk-local C)
// MODE 3: fp32 C = resid + acc + bias  (C/resid pre-offset, may alias)
template<int MODE>
__global__ __launch_bounds__(256)
void gemm_bf16x3(const __hip_bfloat16* __restrict__ A2,
                 const __hip_bfloat16* __restrict__ B2,
                 const float* __restrict__ bias, const float* resid,
                 void* Cout, int M, int N, int K, int mbase)
{
    __shared__ __align__(16) unsigned short Ah[128 * 32];
    __shared__ __align__(16) unsigned short Al[128 * 32];
    __shared__ __align__(16) unsigned short Bh[128 * 32];
    __shared__ __align__(16) unsigned short Bl[128 * 32];

    const int tid  = threadIdx.x;
    const int wave = tid >> 6, lane = tid & 63;

    // XCD-aware bijective remap of the linear block id (q/r chunking, m204)
    const int nwg  = gridDim.x * gridDim.y;
    const int orig = blockIdx.y * gridDim.x + blockIdx.x;
    const int qc   = nwg >> 3, rc = nwg & 7;
    const int xcd  = orig & 7, off = orig >> 3;
    const int lin  = ((xcd < rc) ? xcd * (qc + 1) : rc * (qc + 1) + (xcd - rc) * qc) + off;
    const int m0 = (lin / gridDim.x) * 128, n0 = (lin % gridDim.x) * 128;

    // staging: lane l -> LDS row (l>>2), phys slot (l&3); global src slot
    // must be (l&3) ^ ((row>>1)&3) = (l&3) ^ ((l>>3)&3)
    const int srow = wave * 16 + (lane >> 2);
    const int scol = ((lane & 3) ^ ((lane >> 3) & 3)) * 8;
    const size_t K2 = (size_t)2 * K;
    const __hip_bfloat16* gA0 = A2 + (size_t)(m0 + srow) * K2 + scol;
    const __hip_bfloat16* gB0 = B2 + (size_t)(n0 + srow) * K2 + scol;
    const size_t rstep = (size_t)64 * K2;
    unsigned short* lAh0 = &Ah[(wave * 16) * 32];          // wave-uniform bases
    unsigned short* lAh1 = &Ah[(64 + wave * 16) * 32];
    unsigned short* lAl0 = &Al[(wave * 16) * 32];
    unsigned short* lAl1 = &Al[(64 + wave * 16) * 32];
    unsigned short* lBh0 = &Bh[(wave * 16) * 32];
    unsigned short* lBh1 = &Bh[(64 + wave * 16) * 32];
    unsigned short* lBl0 = &Bl[(wave * 16) * 32];
    unsigned short* lBl1 = &Bl[(64 + wave * 16) * 32];

    // compute: wave (wm,wn) owns 64x64; 4x4 frags of 16x16
    const int wm = (wave >> 1) * 64, wn = (wave & 1) * 64;
    const int fr = lane & 15;
    const int sa = (((lane >> 4) ^ ((fr >> 1) & 3)) * 8);  // swizzled read slot

    f32x4 acc[4][4];
    #pragma unroll
    for (int i = 0; i < 4; ++i)
        #pragma unroll
        for (int j = 0; j < 4; ++j) acc[i][j] = {0.f, 0.f, 0.f, 0.f};

    for (int k0 = 0; k0 < K; k0 += 32) {
        const __hip_bfloat16* a = gA0 + k0;
        const __hip_bfloat16* b = gB0 + k0;
        gload16(a,             lAh0);  gload16(a + rstep,     lAh1);
        gload16(a + K,         lAl0);  gload16(a + K + rstep, lAl1);
        gload16(b,             lBh0);  gload16(b + rstep,     lBh1);
        gload16(b + K,         lBl0);  gload16(b + K + rstep, lBl1);
        __syncthreads();               // drains vmcnt (compiler-inserted)

        short8 ah[4], al[4], bh[4], bl[4];
        #pragma unroll
        for (int f = 0; f < 4; ++f) {
            const int ra = (wm + f * 16 + fr) * 32 + sa;
            const int rb = (wn + f * 16 + fr) * 32 + sa;
            ah[f] = *(const short8*)&Ah[ra];
            al[f] = *(const short8*)&Al[ra];
            bh[f] = *(const short8*)&Bh[rb];
            bl[f] = *(const short8*)&Bl[rb];
        }
        #pragma unroll
        for (int i = 0; i < 4; ++i)
            #pragma unroll
            for (int j = 0; j < 4; ++j) {
                acc[i][j] = __builtin_amdgcn_mfma_f32_16x16x32_bf16(ah[i], bh[j], acc[i][j], 0, 0, 0);
                acc[i][j] = __builtin_amdgcn_mfma_f32_16x16x32_bf16(al[i], bh[j], acc[i][j], 0, 0, 0);
                acc[i][j] = __builtin_amdgcn_mfma_f32_16x16x32_bf16(ah[i], bl[j], acc[i][j], 0, 0, 0);
            }
        __syncthreads();               // reads done before next stage
    }

    // epilogue: C/D layout col=lane&15, row=(lane>>4)*4+reg (m89-verified)
    const int colb = n0 + wn + fr;
    const int rowb = m0 + wm + (lane >> 4) * 4;
    float bv[4];
    #pragma unroll
    for (int j = 0; j < 4; ++j) bv[j] = bias[colb + j * 16];

    #pragma unroll
    for (int i = 0; i < 4; ++i) {
        #pragma unroll
        for (int r = 0; r < 4; ++r) {
            const int row = rowb + i * 16 + r;
            if constexpr (MODE == 0) {
                float* C = (float*)Cout;
                size_t base = (size_t)row * N;
                #pragma unroll
                for (int j = 0; j < 4; ++j)
                    C[base + colb + j * 16] = acc[i][j][r] + bv[j];
            } else if constexpr (MODE == 1) {
                float* C = (float*)Cout;
                size_t base = (size_t)token_to_pixel(mbase + row) * CDIM;
                #pragma unroll
                for (int j = 0; j < 4; ++j) {
                    size_t idx = base + colb + j * 16;
                    C[idx] = resid[idx] + acc[i][j][r] + bv[j];
                }
            } else if constexpr (MODE == 2) {
                __hip_bfloat16* Cb = (__hip_bfloat16*)Cout;
                size_t base = (size_t)row * (2 * N);
                #pragma unroll
                for (int j = 0; j < 4; ++j) {
                    float v = acc[i][j][r] + bv[j];
                    float g = 0.5f * v * (1.0f + erff(v * 0.70710678118654752f));
                    split2(g, Cb[base + colb + j * 16], Cb[base + N + colb + j * 16]);
                }
            } else {  // MODE 3
                float* C = (float*)Cout;
                size_t base = (size_t)row * N;
                #pragma unroll
                for (int j = 0; j < 4; ++j) {
                    size_t idx = base + colb + j * 16;
                    C[idx] = resid[idx] + acc[i][j][r] + bv[j];
                }
            }
        }
    }
}

// ---------------- attention: one block per (window, head), fp32 -----------
// chunk-local qkv in, packed bf16 (hi|lo) chunk-local out
__global__ __launch_bounds__(256)
void attn_kernel(const float* __restrict__ qkv, __hip_bfloat16* __restrict__ o2)
{
    const int blk = blockIdx.x;
    const int w   = blk / NHEADS;
    const int h   = blk % NHEADS;
    const int tid = threadIdx.x;

    __shared__ float qs[SEQ][33], ks[SEQ][33], vs[SEQ][36];
    __shared__ float ps[SEQ][50];
    __shared__ float rmax[SEQ], rsum[SEQ];

    const size_t base = (size_t)w * SEQ * QKVD + h * HDIM;
    for (int i = tid; i < SEQ * HDIM; i += 256) {
        int s = i >> 5, d = i & 31;
        size_t g = base + (size_t)s * QKVD + d;
        qs[s][d] = qkv[g];
        ks[s][d] = qkv[g + CDIM];
        vs[s][d] = qkv[g + 2 * CDIM];
    }
    __syncthreads();

    const float scale = 0.17677669529663687f;   // 1/sqrt(32)
    for (int it = tid; it < SEQ * 7; it += 256) {
        int r = it / 7, cg = (it % 7) * 7;
        float a[7] = {0, 0, 0, 0, 0, 0, 0};
        for (int kk = 0; kk < HDIM; ++kk) {
            float qv = qs[r][kk];
            #pragma unroll
            for (int j = 0; j < 7; ++j) a[j] = fmaf(qv, ks[cg + j][kk], a[j]);
        }
        #pragma unroll
        for (int j = 0; j < 7; ++j) ps[r][cg + j] = a[j] * scale;
    }
    __syncthreads();
    if (tid < SEQ) {
        float m = -1e30f;
        for (int c = 0; c < SEQ; ++c) m = fmaxf(m, ps[tid][c]);
        rmax[tid] = m;
    }
    __syncthreads();
    for (int e = tid; e < SEQ * SEQ; e += 256) {
        int r = e / SEQ, c = e % SEQ;
        ps[r][c] = __expf(ps[r][c] - rmax[r]);
    }
    __syncthreads();
    if (tid < SEQ) {
        float s = 0.f;
        for (int c = 0; c < SEQ; ++c) s += ps[tid][c];
        rsum[tid] = 1.0f / s;
    }
    __syncthreads();
    for (int it = tid; it < SEQ * 4; it += 256) {
        int s = it >> 2, dg = (it & 3) * 8;
        float a[8] = {0, 0, 0, 0, 0, 0, 0, 0};
        for (int t = 0; t < SEQ; ++t) {
            float pv = ps[s][t];
            #pragma unroll
            for (int j = 0; j < 8; ++j) a[j] = fmaf(pv, vs[t][dg + j], a[j]);
        }
        float inv = rsum[s];
        __hip_bfloat16 hv[8], lv[8];
        #pragma unroll
        for (int j = 0; j < 8; ++j) split2(a[j] * inv, hv[j], lv[j]);
        size_t r = ((size_t)w * SEQ + s) * (2 * CDIM) + h * HDIM + dg;
        *(short8*)&o2[r]        = *(short8*)hv;
        *(short8*)&o2[r + CDIM] = *(short8*)lv;
    }
}

// ---------------- launch ---------------------------------------------------
extern "C" void kernel_launch(void* const* d_in, const int* in_sizes, int n_in,
                              void* d_out, int out_size, void* d_ws, size_t ws_size,
                              hipStream_t stream)
{
    const float* x    = (const float*)d_in[0];
    const float* n1w  = (const float*)d_in[3];
    const float* n1b  = (const float*)d_in[4];
    const float* qkvw = (const float*)d_in[5];
    const float* qkvb = (const float*)d_in[6];
    const float* outw = (const float*)d_in[7];
    const float* outb = (const float*)d_in[8];
    const float* n2w  = (const float*)d_in[9];
    const float* n2b  = (const float*)d_in[10];
    const float* fc1w = (const float*)d_in[11];
    const float* fc1b = (const float*)d_in[12];
    const float* fc2w = (const float*)d_in[13];
    const float* fc2b = (const float*)d_in[14];
    float* out = (float*)d_out;

    // ---- adaptive workspace layout ----
    // fixed: packed weights (7,077,888 B). reusable region R, both phases use
    // 7680 B/row:  phase1  win(1536) | qkv(4608) | o(1536)
    //              phase2  h2 (1536) | hid(6144)
    const size_t WBYTES = 7077888;
    char* wsb = (char*)d_ws;
    __hip_bfloat16* wq  = (__hip_bfloat16*)wsb;            //  884,736 el
    __hip_bfloat16* wo  = wq  + 884736;                    //  294,912 el
    __hip_bfloat16* wf1 = wo  + 294912;                    // 1,179,648 el
    __hip_bfloat16* wf2 = wf1 + 1179648;                   // 1,179,648 el
    char* R = wsb + WBYTES;

    // chunk rows: multiples of 49*128=6272 so window & tile boundaries align
    int rows = 6272;
    const int cand[5] = {100352, 50176, 25088, 12544, 6272};
    for (int i = 0; i < 5; ++i)
        if (WBYTES + (size_t)cand[i] * 7680 <= ws_size) { rows = cand[i]; break; }
    const int nch = TOKENS / rows;

    __hip_bfloat16* win_b = (__hip_bfloat16*)R;
    float*          qkv_b = (float*)(R + (size_t)rows * 1536);
    __hip_bfloat16* o_b   = (__hip_bfloat16*)(R + (size_t)rows * 6144);
    __hip_bfloat16* h2_b  = (__hip_bfloat16*)R;
    __hip_bfloat16* hid_b = (__hip_bfloat16*)(R + (size_t)rows * 1536);

    // 0. pack weights (hi|lo bf16)
    pack_w_kernel<<<1728, 256, 0, stream>>>(qkvw, wq,  QKVD, CDIM);
    pack_w_kernel<<<576,  256, 0, stream>>>(outw, wo,  CDIM, CDIM);
    pack_w_kernel<<<2304, 256, 0, stream>>>(fc1w, wf1, HIDD, CDIM);
    pack_w_kernel<<<2304, 256, 0, stream>>>(fc2w, wf2, CDIM, HIDD);

    // phase 1: LN1+shift+window -> qkv -> attention -> proj+unshift+resid
    for (int c = 0; c < nch; ++c) {
        const int mb = c * rows;
        ln_pack_kernel<1><<<rows, 128, 0, stream>>>(x, n1w, n1b, win_b, mb);
        gemm_bf16x3<0><<<dim3(QKVD / 128, rows / 128), 256, 0, stream>>>(
            win_b, wq, qkvb, nullptr, qkv_b, rows, QKVD, CDIM, 0);
        attn_kernel<<<(rows / SEQ) * NHEADS, 256, 0, stream>>>(qkv_b, o_b);
        gemm_bf16x3<1><<<dim3(CDIM / 128, rows / 128), 256, 0, stream>>>(
            o_b, wo, outb, x, out, rows, CDIM, CDIM, mb);
    }
    // phase 2: LN2 -> fc1+gelu -> fc2+resid (in-place on d_out)
    for (int c = 0; c < nch; ++c) {
        const int mb = c * rows;
        float* oc = out + (size_t)mb * CDIM;
        ln_pack_kernel<0><<<rows, 128, 0, stream>>>(oc, n2w, n2b, h2_b, 0);
        gemm_bf16x3<2><<<dim3(HIDD / 128, rows / 128), 256, 0, stream>>>(
            h2_b, wf1, fc1b, nullptr, hid_b, rows, HIDD, CDIM, 0);
        gemm_bf16x3<3><<<dim3(CDIM / 128, rows / 128), 256, 0, stream>>>(
            hid_b, wf2, fc2b, oc, oc, rows, CDIM, HIDD, 0);
    }
}

// Round 9
// 2277.950 us; speedup vs baseline: 1.0561x; 1.0561x over previous
//
#include <hip/hip_runtime.h>
#include <hip/hip_bf16.h>
#include <math.h>

// ---- problem constants (B=32, H=W=56, C=384, WS=7, SHIFT=3) ----
#define TOKENS   100352      // 32 * 56 * 56
#define CDIM     384
#define SEQ      49
#define NHEADS   12
#define HDIM     32
#define QKVD     1152
#define HIDD     1536
#define IMG      56

typedef __attribute__((ext_vector_type(8))) short  short8;   // 8 bf16 (4 VGPRs)
typedef __attribute__((ext_vector_type(4))) float  f32x4;    // MFMA C/D

// window-token index -> pixel-row index (same (+3 mod 56) bijection fwd & inv)
__device__ __forceinline__ int token_to_pixel(int m) {
    int w  = m / SEQ, s = m % SEQ;
    int b  = w >> 6, wr = w & 63;
    int wy = wr >> 3, wx = wr & 7;
    int sy = s / 7,  sx = s % 7;
    int y = wy * 7 + sy + 3; if (y >= IMG) y -= IMG;
    int x = wx * 7 + sx + 3; if (x >= IMG) x -= IMG;
    return b * (IMG * IMG) + y * IMG + x;
}

// fp32 -> (hi, lo) bf16 split:  v ~= hi + lo, |lo| <= 2^-9 |v|
__device__ __forceinline__ void split2(float v, __hip_bfloat16& hi, __hip_bfloat16& lo) {
    hi = __float2bfloat16(v);
    lo = __float2bfloat16(v - __bfloat162float(hi));
}

// async global->LDS, 16B per lane; LDS base must be wave-uniform
__device__ __forceinline__ void gload16(const void* g, void* l) {
    __builtin_amdgcn_global_load_lds((const __attribute__((address_space(1))) void*)g,
                                     (__attribute__((address_space(3))) void*)l, 16, 0, 0);
}

// ---------------- LayerNorm -> packed [local_m][2*384] bf16 (hi|lo) --------
// WINDOWED=1: gather x[pixel(mbase+bid)] (LN1+shift+window)
// WINDOWED=0: in is pre-offset to the chunk; reads row bid (LN2)
template<int WINDOWED>
__global__ __launch_bounds__(128)
void ln_pack_kernel(const float* __restrict__ in, const float* __restrict__ w,
                    const float* __restrict__ b, __hip_bfloat16* __restrict__ out,
                    int mbase)
{
    const int ml  = blockIdx.x;
    const int src = WINDOWED ? token_to_pixel(mbase + ml) : ml;
    const float* row = in + (size_t)src * CDIM;
    const int t = threadIdx.x;

    float v0 = row[t], v1 = row[t + 128], v2 = row[t + 256];
    float s  = v0 + v1 + v2;
    float ss = fmaf(v0, v0, fmaf(v1, v1, v2 * v2));
    #pragma unroll
    for (int off = 1; off < 64; off <<= 1) {
        s  += __shfl_xor(s,  off, 64);
        ss += __shfl_xor(ss, off, 64);
    }
    __shared__ float l1[2], l2[2];
    if ((t & 63) == 0) { l1[t >> 6] = s; l2[t >> 6] = ss; }
    __syncthreads();
    float S  = l1[0] + l1[1];
    float SS = l2[0] + l2[1];
    float mean = S * (1.0f / CDIM);
    float var  = SS * (1.0f / CDIM) - mean * mean;
    float rstd = rsqrtf(var + 1e-5f);

    __hip_bfloat16* orow = out + (size_t)ml * (2 * CDIM);
    #pragma unroll
    for (int q = 0; q < 3; ++q) {
        int c = t + q * 128;
        float v = (q == 0 ? v0 : q == 1 ? v1 : v2);
        float y = (v - mean) * rstd * w[c] + b[c];
        split2(y, orow[c], orow[CDIM + c]);
    }
}

// ---------------- weight fp32 [N][K] -> packed bf16 [N][2K] (hi|lo) --------
__global__ __launch_bounds__(256)
void pack_w_kernel(const float* __restrict__ W, __hip_bfloat16* __restrict__ Wp,
                   int N, int K)
{
    const int total = N * K;
    for (int i = blockIdx.x * 256 + threadIdx.x; i < total; i += gridDim.x * 256) {
        int n = i / K, k = i % K;
        split2(W[i], Wp[(size_t)n * 2 * K + k], Wp[(size_t)n * 2 * K + K + k]);
    }
}

// ---------------- bf16x3 split GEMM: C[M,N] = A[M,K] @ B[N,K]^T ------------
// A2 [M][2K], B2 [N][2K] packed bf16 (hi|lo). Single K-sweep; per 32-wide
// K-step stages A-hi/A-lo/B-hi/B-lo together, 48 MFMAs per barrier.
// 2-PHASE PIPELINE: stage step t+1 into the alternate LDS set before
// computing step t; ONE barrier per step (its vmcnt/lgkm drain covers both
// "next staged" and "current reads done" hazards). 64 KB LDS.
// Tile order: XCD-chunked (contiguous tile range per XCD) then supertiled
// (bands of SH rows x strips of SW cols, row-major within strip) so the
// concurrent working set per XCD L2 is SH A-panels + SW B-panels.
// LDS slot swizzle (both-sides): LDS[row][p] holds global slot p^((row>>1)&3).
// MODE 0: fp32 C = acc + bias                       (qkv, chunk-local C)
// MODE 1: scatter fp32 C[pix(mbase+row)] = resid+acc+b  (proj+unwindow+resid)
// MODE 2: packed bf16 C = split(gelu(acc + bias))   (fc1, chunk-local C)
// MODE 3: fp32 C = resid + acc + bias  (C/resid pre-offset, may alias)
template<int MODE>
__global__ __launch_bounds__(256)
void gemm_bf16x3(const __hip_bfloat16* __restrict__ A2,
                 const __hip_bfloat16* __restrict__ B2,
                 const float* __restrict__ bias, const float* resid,
                 void* Cout, int M, int N, int K, int mbase, int SH_, int SW_)
{
    __shared__ __align__(16) unsigned short Ah[2][4096];
    __shared__ __align__(16) unsigned short Al[2][4096];
    __shared__ __align__(16) unsigned short Bh[2][4096];
    __shared__ __align__(16) unsigned short Bl[2][4096];

    const int tid  = threadIdx.x;
    const int wave = tid >> 6, lane = tid & 63;

    // ---- XCD-aware bijective remap (contiguous tile range per XCD) -------
    const int nwg  = gridDim.x * gridDim.y;
    const int orig = blockIdx.y * gridDim.x + blockIdx.x;
    const int qc   = nwg >> 3, r8 = nwg & 7;
    const int xcd  = orig & 7, off = orig >> 3;
    const int lin  = ((xcd < r8) ? xcd * (qc + 1) : r8 * (qc + 1) + (xcd - r8) * qc) + off;

    // ---- supertile decode: lin -> (tile row, tile col), bijective --------
    const int gx = gridDim.x, gy = gridDim.y;
    const int band  = lin / (SH_ * gx);
    const int sh    = min(SH_, gy - band * SH_);
    const int rr    = lin - band * SH_ * gx;
    const int strip = rr / (sh * SW_);
    const int sw    = min(SW_, gx - strip * SW_);
    const int r2    = rr - strip * sh * SW_;
    const int m0 = (band * SH_ + r2 / sw) * 128;
    const int n0 = (strip * SW_ + r2 % sw) * 128;

    // staging: lane l -> LDS row (l>>2), phys slot (l&3); global src slot
    // must be (l&3) ^ ((row>>1)&3) = (l&3) ^ ((l>>3)&3)
    const int srow = wave * 16 + (lane >> 2);
    const int scol = ((lane & 3) ^ ((lane >> 3) & 3)) * 8;
    const size_t K2 = (size_t)2 * K;
    const __hip_bfloat16* gA0 = A2 + (size_t)(m0 + srow) * K2 + scol;
    const __hip_bfloat16* gB0 = B2 + (size_t)(n0 + srow) * K2 + scol;
    const size_t rstep = (size_t)64 * K2;
    const int lA0 = (wave * 16) * 32;            // wave-uniform LDS offsets
    const int lA1 = (64 + wave * 16) * 32;

#define STAGE(k0, s) do {                                                     \
        const __hip_bfloat16* a_ = gA0 + (k0);                                \
        const __hip_bfloat16* b_ = gB0 + (k0);                                \
        gload16(a_,             &Ah[s][lA0]); gload16(a_ + rstep,     &Ah[s][lA1]); \
        gload16(a_ + K,         &Al[s][lA0]); gload16(a_ + K + rstep, &Al[s][lA1]); \
        gload16(b_,             &Bh[s][lA0]); gload16(b_ + rstep,     &Bh[s][lA1]); \
        gload16(b_ + K,         &Bl[s][lA0]); gload16(b_ + K + rstep, &Bl[s][lA1]); \
    } while (0)

    // compute: wave (wm,wn) owns 64x64; 4x4 frags of 16x16
    const int wm = (wave >> 1) * 64, wn = (wave & 1) * 64;
    const int fr = lane & 15;
    const int sa = (((lane >> 4) ^ ((fr >> 1) & 3)) * 8);  // swizzled read slot

    f32x4 acc[4][4];
    #pragma unroll
    for (int i = 0; i < 4; ++i)
        #pragma unroll
        for (int j = 0; j < 4; ++j) acc[i][j] = {0.f, 0.f, 0.f, 0.f};

    const int ksteps = K >> 5;
    STAGE(0, 0);
    __syncthreads();                       // drain prologue staging
    int cur = 0;
    for (int t = 0; t < ksteps; ++t) {
        const int nxt = cur ^ 1;
        if (t + 1 < ksteps) STAGE((t + 1) << 5, nxt);   // prefetch next step

        short8 ah[4], al[4], bh[4], bl[4];
        #pragma unroll
        for (int f = 0; f < 4; ++f) {
            const int ra = (wm + f * 16 + fr) * 32 + sa;
            const int rb = (wn + f * 16 + fr) * 32 + sa;
            ah[f] = *(const short8*)&Ah[cur][ra];
            al[f] = *(const short8*)&Al[cur][ra];
            bh[f] = *(const short8*)&Bh[cur][rb];
            bl[f] = *(const short8*)&Bl[cur][rb];
        }
        #pragma unroll
        for (int i = 0; i < 4; ++i)
            #pragma unroll
            for (int j = 0; j < 4; ++j) {
                acc[i][j] = __builtin_amdgcn_mfma_f32_16x16x32_bf16(ah[i], bh[j], acc[i][j], 0, 0, 0);
                acc[i][j] = __builtin_amdgcn_mfma_f32_16x16x32_bf16(al[i], bh[j], acc[i][j], 0, 0, 0);
                acc[i][j] = __builtin_amdgcn_mfma_f32_16x16x32_bf16(ah[i], bl[j], acc[i][j], 0, 0, 0);
            }
        __syncthreads();                   // next staged + current reads done
        cur = nxt;
    }
#undef STAGE

    // epilogue: C/D layout col=lane&15, row=(lane>>4)*4+reg (m89-verified)
    const int colb = n0 + wn + fr;
    const int rowb = m0 + wm + (lane >> 4) * 4;
    float bv[4];
    #pragma unroll
    for (int j = 0; j < 4; ++j) bv[j] = bias[colb + j * 16];

    #pragma unroll
    for (int i = 0; i < 4; ++i) {
        #pragma unroll
        for (int r = 0; r < 4; ++r) {
            const int row = rowb + i * 16 + r;
            if constexpr (MODE == 0) {
                float* C = (float*)Cout;
                size_t base = (size_t)row * N;
                #pragma unroll
                for (int j = 0; j < 4; ++j)
                    C[base + colb + j * 16] = acc[i][j][r] + bv[j];
            } else if constexpr (MODE == 1) {
                float* C = (float*)Cout;
                size_t base = (size_t)token_to_pixel(mbase + row) * CDIM;
                #pragma unroll
                for (int j = 0; j < 4; ++j) {
                    size_t idx = base + colb + j * 16;
                    C[idx] = resid[idx] + acc[i][j][r] + bv[j];
                }
            } else if constexpr (MODE == 2) {
                __hip_bfloat16* Cb = (__hip_bfloat16*)Cout;
                size_t base = (size_t)row * (2 * N);
                #pragma unroll
                for (int j = 0; j < 4; ++j) {
                    float v = acc[i][j][r] + bv[j];
                    float g = 0.5f * v * (1.0f + erff(v * 0.70710678118654752f));
                    split2(g, Cb[base + colb + j * 16], Cb[base + N + colb + j * 16]);
                }
            } else {  // MODE 3
                float* C = (float*)Cout;
                size_t base = (size_t)row * N;
                #pragma unroll
                for (int j = 0; j < 4; ++j) {
                    size_t idx = base + colb + j * 16;
                    C[idx] = resid[idx] + acc[i][j][r] + bv[j];
                }
            }
        }
    }
}

// ---------------- attention: one block per (window, head), fp32 -----------
// chunk-local qkv in, packed bf16 (hi|lo) chunk-local out
__global__ __launch_bounds__(256)
void attn_kernel(const float* __restrict__ qkv, __hip_bfloat16* __restrict__ o2)
{
    const int blk = blockIdx.x;
    const int w   = blk / NHEADS;
    const int h   = blk % NHEADS;
    const int tid = threadIdx.x;

    __shared__ float qs[SEQ][33], ks[SEQ][33], vs[SEQ][36];
    __shared__ float ps[SEQ][50];
    __shared__ float rmax[SEQ], rsum[SEQ];

    const size_t base = (size_t)w * SEQ * QKVD + h * HDIM;
    for (int i = tid; i < SEQ * HDIM; i += 256) {
        int s = i >> 5, d = i & 31;
        size_t g = base + (size_t)s * QKVD + d;
        qs[s][d] = qkv[g];
        ks[s][d] = qkv[g + CDIM];
        vs[s][d] = qkv[g + 2 * CDIM];
    }
    __syncthreads();

    const float scale = 0.17677669529663687f;   // 1/sqrt(32)
    for (int it = tid; it < SEQ * 7; it += 256) {
        int r = it / 7, cg = (it % 7) * 7;
        float a[7] = {0, 0, 0, 0, 0, 0, 0};
        for (int kk = 0; kk < HDIM; ++kk) {
            float qv = qs[r][kk];
            #pragma unroll
            for (int j = 0; j < 7; ++j) a[j] = fmaf(qv, ks[cg + j][kk], a[j]);
        }
        #pragma unroll
        for (int j = 0; j < 7; ++j) ps[r][cg + j] = a[j] * scale;
    }
    __syncthreads();
    if (tid < SEQ) {
        float m = -1e30f;
        for (int c = 0; c < SEQ; ++c) m = fmaxf(m, ps[tid][c]);
        rmax[tid] = m;
    }
    __syncthreads();
    for (int e = tid; e < SEQ * SEQ; e += 256) {
        int r = e / SEQ, c = e % SEQ;
        ps[r][c] = __expf(ps[r][c] - rmax[r]);
    }
    __syncthreads();
    if (tid < SEQ) {
        float s = 0.f;
        for (int c = 0; c < SEQ; ++c) s += ps[tid][c];
        rsum[tid] = 1.0f / s;
    }
    __syncthreads();
    for (int it = tid; it < SEQ * 4; it += 256) {
        int s = it >> 2, dg = (it & 3) * 8;
        float a[8] = {0, 0, 0, 0, 0, 0, 0, 0};
        for (int t = 0; t < SEQ; ++t) {
            float pv = ps[s][t];
            #pragma unroll
            for (int j = 0; j < 8; ++j) a[j] = fmaf(pv, vs[t][dg + j], a[j]);
        }
        float inv = rsum[s];
        __hip_bfloat16 hv[8], lv[8];
        #pragma unroll
        for (int j = 0; j < 8; ++j) split2(a[j] * inv, hv[j], lv[j]);
        size_t r = ((size_t)w * SEQ + s) * (2 * CDIM) + h * HDIM + dg;
        *(short8*)&o2[r]        = *(short8*)hv;
        *(short8*)&o2[r + CDIM] = *(short8*)lv;
    }
}

// ---------------- launch ---------------------------------------------------
extern "C" void kernel_launch(void* const* d_in, const int* in_sizes, int n_in,
                              void* d_out, int out_size, void* d_ws, size_t ws_size,
                              hipStream_t stream)
{
    const float* x    = (const float*)d_in[0];
    const float* n1w  = (const float*)d_in[3];
    const float* n1b  = (const float*)d_in[4];
    const float* qkvw = (const float*)d_in[5];
    const float* qkvb = (const float*)d_in[6];
    const float* outw = (const float*)d_in[7];
    const float* outb = (const float*)d_in[8];
    const float* n2w  = (const float*)d_in[9];
    const float* n2b  = (const float*)d_in[10];
    const float* fc1w = (const float*)d_in[11];
    const float* fc1b = (const float*)d_in[12];
    const float* fc2w = (const float*)d_in[13];
    const float* fc2b = (const float*)d_in[14];
    float* out = (float*)d_out;

    // ---- workspace: packed weights (7,077,888 B) + reusable region R ----
    // phase-1: 6144 B/row  (win 1536 | qkv 4608; attn-out o ALIASES win,
    //          legal since win is dead once the qkv GEMM has run)
    // phase-2: 7680 B/row  (h2 1536 | hid 6144)
    const size_t WBYTES = 7077888;
    char* wsb = (char*)d_ws;
    __hip_bfloat16* wq  = (__hip_bfloat16*)wsb;
    __hip_bfloat16* wo  = wq  + 884736;
    __hip_bfloat16* wf1 = wo  + 294912;
    __hip_bfloat16* wf2 = wf1 + 1179648;
    char* R = wsb + WBYTES;
    const size_t avail = ws_size - WBYTES;

    // chunk rows: phase-1 multiples of lcm(49,128)=6272, phase-2 of 128
    int r1 = 6272;
    while (r1 < TOKENS && (size_t)(r1 + 6272) * 6144 <= avail) r1 += 6272;
    int r2 = 128;
    while (r2 < TOKENS && (size_t)(r2 + 128) * 7680 <= avail) r2 += 128;

    // 0. pack weights (hi|lo bf16)
    pack_w_kernel<<<1728, 256, 0, stream>>>(qkvw, wq,  QKVD, CDIM);
    pack_w_kernel<<<576,  256, 0, stream>>>(outw, wo,  CDIM, CDIM);
    pack_w_kernel<<<2304, 256, 0, stream>>>(fc1w, wf1, HIDD, CDIM);
    pack_w_kernel<<<2304, 256, 0, stream>>>(fc2w, wf2, CDIM, HIDD);

    // phase 1: LN1+shift+window -> qkv -> attention -> proj+unshift+resid
    {
        __hip_bfloat16* win_b = (__hip_bfloat16*)R;
        float*          qkv_b = (float*)(R + (size_t)r1 * 1536);
        __hip_bfloat16* o_b   = win_b;                       // alias (win dead)
        for (int mb = 0; mb < TOKENS; mb += r1) {
            const int rc = min(r1, TOKENS - mb);             // multiple of 6272
            ln_pack_kernel<1><<<rc, 128, 0, stream>>>(x, n1w, n1b, win_b, mb);
            gemm_bf16x3<0><<<dim3(QKVD / 128, rc / 128), 256, 0, stream>>>(
                win_b, wq, qkvb, nullptr, qkv_b, rc, QKVD, CDIM, 0, 4, 9);
            attn_kernel<<<(rc / SEQ) * NHEADS, 256, 0, stream>>>(qkv_b, o_b);
            gemm_bf16x3<1><<<dim3(CDIM / 128, rc / 128), 256, 0, stream>>>(
                o_b, wo, outb, x, out, rc, CDIM, CDIM, mb, 8, 3);
        }
    }
    // phase 2: LN2 -> fc1+gelu -> fc2+resid (in-place on d_out)
    {
        __hip_bfloat16* h2_b  = (__hip_bfloat16*)R;
        __hip_bfloat16* hid_b = (__hip_bfloat16*)(R + (size_t)r2 * 1536);
        for (int mb = 0; mb < TOKENS; mb += r2) {
            const int rc = min(r2, TOKENS - mb);             // multiple of 128
            float* oc = out + (size_t)mb * CDIM;
            ln_pack_kernel<0><<<rc, 128, 0, stream>>>(oc, n2w, n2b, h2_b, 0);
            gemm_bf16x3<2><<<dim3(HIDD / 128, rc / 128), 256, 0, stream>>>(
                h2_b, wf1, fc1b, nullptr, hid_b, rc, HIDD, CDIM, 0, 4, 12);
            gemm_bf16x3<3><<<dim3(CDIM / 128, rc / 128), 256, 0, stream>>>(
                hid_b, wf2, fc2b, oc, oc, rc, CDIM, HIDD, 0, 2, 3);
        }
    }
}